// Round 5
// baseline (699.375 us; speedup 1.0000x reference)
//
#include <hip/hip_runtime.h>

#define NN 50000
#define NE 800000
#define NG 256
#define NBUCKET 64
#define HCHUNK 8192
#define HBLK 4
#define NCHUNK ((NN + HCHUNK - 1) / HCHUNK)   // 7

// ---------------- prologue ----------------
// cnt=0, part buckets = 0
__global__ void k_init(int* cnt, float* part, int n) {
    int i = blockIdx.x * blockDim.x + threadIdx.x;
    if (i < n) cnt[i] = 0;
    if (i < NBUCKET * 256) part[i] = 0.f;
}

// chunked LDS-privatized histogram of col[] -> cnt[]
__global__ void k_hist(const int* __restrict__ col, int* __restrict__ cnt, int e) {
    __shared__ int h[HCHUNK];
    int chunk = blockIdx.x / HBLK, slice = blockIdx.x % HBLK;
    int base = chunk * HCHUNK;
    for (int j = threadIdx.x; j < HCHUNK; j += 256) h[j] = 0;
    __syncthreads();
    for (int i = slice * 256 + threadIdx.x; i < e; i += HBLK * 256) {
        int c = col[i] - base;
        if ((unsigned)c < HCHUNK) atomicAdd(&h[c], 1);
    }
    __syncthreads();
    int lim = min(HCHUNK, NN - base);
    for (int j = threadIdx.x; j < lim; j += 256) {
        int v = h[j];
        if (v) atomicAdd(&cnt[base + j], v);
    }
}

__global__ void k_scan1(const int* __restrict__ in, int* __restrict__ out,
                        int* __restrict__ bsum, int n) {
    __shared__ int s[256];
    int i = blockIdx.x * 256 + threadIdx.x;
    int v = (i < n) ? in[i] : 0;
    s[threadIdx.x] = v;
    __syncthreads();
    for (int off = 1; off < 256; off <<= 1) {
        int t = (threadIdx.x >= off) ? s[threadIdx.x - off] : 0;
        __syncthreads();
        s[threadIdx.x] += t;
        __syncthreads();
    }
    if (i < n) out[i] = s[threadIdx.x] - v;  // exclusive
    if (threadIdx.x == 255) bsum[blockIdx.x] = s[255];
}

__global__ void k_scan2(int* bsum, int nb) {
    __shared__ int s[256];
    int v = (threadIdx.x < nb) ? bsum[threadIdx.x] : 0;
    s[threadIdx.x] = v;
    __syncthreads();
    for (int off = 1; off < 256; off <<= 1) {
        int t = (threadIdx.x >= off) ? s[threadIdx.x - off] : 0;
        __syncthreads();
        s[threadIdx.x] += t;
        __syncthreads();
    }
    if (threadIdx.x < nb) bsum[threadIdx.x] = s[threadIdx.x] - v;
}

__global__ void k_scan3(int* __restrict__ ptr, const int* __restrict__ bsum, int n, int total) {
    int i = blockIdx.x * 256 + threadIdx.x;
    if (i < n) ptr[i] += bsum[blockIdx.x];
    if (i == 0) ptr[n] = total;
}

__global__ void k_copy_int(const int* __restrict__ a, int* __restrict__ b, int n) {
    int i = blockIdx.x * blockDim.x + threadIdx.x;
    if (i < n) b[i] = a[i];
}

// place edges: csr[p] = {src, raw ew}; cursor pre-loaded with ptr
__global__ void k_fill(const int* __restrict__ row, const int* __restrict__ col,
                       const float* __restrict__ ew, int* cursor, int2* __restrict__ csr, int e) {
    int i = blockIdx.x * blockDim.x + threadIdx.x;
    if (i < e) {
        int c = col[i];
        int p = atomicAdd(&cursor[c], 1);
        csr[p] = make_int2(row[i], __float_as_int(ew[i]));
    }
}

// deg[c] = 1 (self loop) + sum of raw ew over segment; dis = rsqrt (atomic-free)
__global__ void k_degdis(const int* __restrict__ ptr, const int2* __restrict__ csr,
                         float* __restrict__ dis, int n) {
    int i = blockIdx.x * blockDim.x + threadIdx.x;
    if (i >= n) return;
    float s = 1.0f;
    int p1 = ptr[i + 1];
    for (int p = ptr[i]; p < p1; ++p) s += __int_as_float(csr[p].y);
    dis[i] = rsqrtf(s);   // s >= 1 > 0 always
}

// csr[p].w *= dis[src]*dis[c]  (in place)
__global__ void k_scale(const int* __restrict__ ptr, int2* __restrict__ csr,
                        const float* __restrict__ dis, int n) {
    int i = blockIdx.x * blockDim.x + threadIdx.x;
    if (i >= n) return;
    float dc = dis[i];
    int p1 = ptr[i + 1];
    for (int p = ptr[i]; p < p1; ++p) {
        int2 v = csr[p];
        csr[p].y = __float_as_int(dis[v.x] * __int_as_float(v.y) * dc);
    }
}

// ---------------- gather ----------------
// POSTAFF (L2/L3/L4): out = sc*A + sh*(dis^2 + sum w)   [BN linear, hoisted]
// PREAFF  (L5): per-edge relu(sc*u+sh)
// EPI     (L1): out = relu(A + bias), channel stats into buckets
template <int D, int POSTAFF, int PREAFF, int EPI>
__global__ void k_gather(const float* __restrict__ src, const int* __restrict__ ptr,
                         const int2* __restrict__ csr,
                         const float* __restrict__ dis,
                         const float* __restrict__ scale, const float* __restrict__ shift,
                         const float* __restrict__ bias, float* __restrict__ part,
                         float* __restrict__ out, int n) {
    const int TPN = D / 4;
    __shared__ float ls[EPI ? D : 1], lq[EPI ? D : 1];
    int tid = threadIdx.x;
    if (EPI) {
        if (tid < D) { ls[tid] = 0.f; lq[tid] = 0.f; }
        __syncthreads();
    }
    int t = blockIdx.x * blockDim.x + tid;
    int node = t / TPN;
    int l4 = t - node * TPN;
    bool valid = node < n;
    int nc = valid ? node : n - 1;

    float4 sc = {0,0,0,0}, sh = {0,0,0,0};
    if (POSTAFF || PREAFF) {
        sc = ((const float4*)scale)[l4];
        sh = ((const float4*)shift)[l4];
    }
    const float4* s4 = (const float4*)src;
    float d = dis[nc];
    float w0 = d * d;
    float4 v = s4[nc * TPN + l4];
    if (PREAFF) {
        v.x = fmaxf(sc.x * v.x + sh.x, 0.f); v.y = fmaxf(sc.y * v.y + sh.y, 0.f);
        v.z = fmaxf(sc.z * v.z + sh.z, 0.f); v.w = fmaxf(sc.w * v.w + sh.w, 0.f);
    }
    float4 acc = { w0 * v.x, w0 * v.y, w0 * v.z, w0 * v.w };
    float sumw = w0;
    int p0 = ptr[nc], p1 = ptr[nc + 1];
    int p = p0;
    for (; p + 4 <= p1; p += 4) {
        int2 c0 = csr[p], c1 = csr[p+1], c2 = csr[p+2], c3 = csr[p+3];
        float e0 = __int_as_float(c0.y), e1 = __int_as_float(c1.y);
        float e2 = __int_as_float(c2.y), e3 = __int_as_float(c3.y);
        float4 u0 = s4[c0.x * TPN + l4];
        float4 u1 = s4[c1.x * TPN + l4];
        float4 u2 = s4[c2.x * TPN + l4];
        float4 u3 = s4[c3.x * TPN + l4];
        if (PREAFF) {
            u0.x = fmaxf(sc.x*u0.x+sh.x,0.f); u0.y = fmaxf(sc.y*u0.y+sh.y,0.f);
            u0.z = fmaxf(sc.z*u0.z+sh.z,0.f); u0.w = fmaxf(sc.w*u0.w+sh.w,0.f);
            u1.x = fmaxf(sc.x*u1.x+sh.x,0.f); u1.y = fmaxf(sc.y*u1.y+sh.y,0.f);
            u1.z = fmaxf(sc.z*u1.z+sh.z,0.f); u1.w = fmaxf(sc.w*u1.w+sh.w,0.f);
            u2.x = fmaxf(sc.x*u2.x+sh.x,0.f); u2.y = fmaxf(sc.y*u2.y+sh.y,0.f);
            u2.z = fmaxf(sc.z*u2.z+sh.z,0.f); u2.w = fmaxf(sc.w*u2.w+sh.w,0.f);
            u3.x = fmaxf(sc.x*u3.x+sh.x,0.f); u3.y = fmaxf(sc.y*u3.y+sh.y,0.f);
            u3.z = fmaxf(sc.z*u3.z+sh.z,0.f); u3.w = fmaxf(sc.w*u3.w+sh.w,0.f);
        }
        acc.x += e0*u0.x + e1*u1.x + e2*u2.x + e3*u3.x;
        acc.y += e0*u0.y + e1*u1.y + e2*u2.y + e3*u3.y;
        acc.z += e0*u0.z + e1*u1.z + e2*u2.z + e3*u3.z;
        acc.w += e0*u0.w + e1*u1.w + e2*u2.w + e3*u3.w;
        if (POSTAFF) sumw += e0 + e1 + e2 + e3;
    }
    for (; p < p1; ++p) {
        int2 ce = csr[p];
        float w = __int_as_float(ce.y);
        float4 u = s4[ce.x * TPN + l4];
        if (PREAFF) {
            u.x = fmaxf(sc.x*u.x+sh.x,0.f); u.y = fmaxf(sc.y*u.y+sh.y,0.f);
            u.z = fmaxf(sc.z*u.z+sh.z,0.f); u.w = fmaxf(sc.w*u.w+sh.w,0.f);
        }
        acc.x += w*u.x; acc.y += w*u.y; acc.z += w*u.z; acc.w += w*u.w;
        if (POSTAFF) sumw += w;
    }
    if (POSTAFF) {
        acc.x = sc.x * acc.x + sh.x * sumw;
        acc.y = sc.y * acc.y + sh.y * sumw;
        acc.z = sc.z * acc.z + sh.z * sumw;
        acc.w = sc.w * acc.w + sh.w * sumw;
    }
    if (EPI) {
        float4 b = ((const float4*)bias)[l4];
        acc.x = fmaxf(acc.x + b.x, 0.f);
        acc.y = fmaxf(acc.y + b.y, 0.f);
        acc.z = fmaxf(acc.z + b.z, 0.f);
        acc.w = fmaxf(acc.w + b.w, 0.f);
        if (valid) ((float4*)out)[nc * TPN + l4] = acc;
        float s0 = valid ? acc.x : 0.f, s1 = valid ? acc.y : 0.f;
        float s2 = valid ? acc.z : 0.f, s3 = valid ? acc.w : 0.f;
        float q0 = s0*s0, q1 = s1*s1, q2 = s2*s2, q3 = s3*s3;
        for (int off = TPN; off < 64; off <<= 1) {
            s0 += __shfl_down(s0, off, 64); s1 += __shfl_down(s1, off, 64);
            s2 += __shfl_down(s2, off, 64); s3 += __shfl_down(s3, off, 64);
            q0 += __shfl_down(q0, off, 64); q1 += __shfl_down(q1, off, 64);
            q2 += __shfl_down(q2, off, 64); q3 += __shfl_down(q3, off, 64);
        }
        int lane = tid & 63;
        if (lane < TPN) {
            atomicAdd(&ls[4*lane+0], s0); atomicAdd(&ls[4*lane+1], s1);
            atomicAdd(&ls[4*lane+2], s2); atomicAdd(&ls[4*lane+3], s3);
            atomicAdd(&lq[4*lane+0], q0); atomicAdd(&lq[4*lane+1], q1);
            atomicAdd(&lq[4*lane+2], q2); atomicAdd(&lq[4*lane+3], q3);
        }
        __syncthreads();
        int bkt = (blockIdx.x & (NBUCKET - 1)) * 256;
        if (tid < D) {
            atomicAdd(&part[bkt + tid], ls[tid]);
            atomicAdd(&part[bkt + 128 + tid], lq[tid]);
        }
    } else {
        if (valid) ((float4*)out)[nc * TPN + l4] = acc;
    }
}

// ---------------- node-blocked GEMM: NPT nodes x 4 outputs per thread ----------------
template <int DIN, int DOUT, int RELU, int EPI, int NPT>
__global__ void k_gemm(const float* __restrict__ h, const float* __restrict__ W,
                       const float* __restrict__ bias, float* __restrict__ part,
                       float* __restrict__ m, int n) {
    const int TPN = DOUT / 4;
    const int GPB = 256 / TPN;
    __shared__ float Wl[DIN * DOUT];
    __shared__ float ls[EPI ? DOUT : 1], lq[EPI ? DOUT : 1];
    int tid = threadIdx.x;
    for (int i = tid; i < DIN * DOUT / 4; i += 256)
        ((float4*)Wl)[i] = ((const float4*)W)[i];
    if (EPI && tid < DOUT) { ls[tid] = 0.f; lq[tid] = 0.f; }
    __syncthreads();

    int jq = tid % TPN;
    int group = tid / TPN;
    int node0 = (blockIdx.x * GPB + group) * NPT;
    const float4* h4 = (const float4*)h;
    int hb[NPT];
    bool val[NPT];
#pragma unroll
    for (int i = 0; i < NPT; ++i) {
        int nd = node0 + i;
        val[i] = nd < n;
        hb[i] = (val[i] ? nd : n - 1) * (DIN / 4);
    }
    float4 acc[NPT];
#pragma unroll
    for (int i = 0; i < NPT; ++i) acc[i] = {0.f, 0.f, 0.f, 0.f};

#pragma unroll 4
    for (int k4 = 0; k4 < DIN / 4; ++k4) {
        const float* wb = &Wl[(k4 * 4) * DOUT + jq * 4];
        float4 w0 = *(const float4*)(wb);
        float4 w1 = *(const float4*)(wb + DOUT);
        float4 w2 = *(const float4*)(wb + 2 * DOUT);
        float4 w3 = *(const float4*)(wb + 3 * DOUT);
#pragma unroll
        for (int i = 0; i < NPT; ++i) {
            float4 hv = h4[hb[i] + k4];
            acc[i].x += hv.x*w0.x + hv.y*w1.x + hv.z*w2.x + hv.w*w3.x;
            acc[i].y += hv.x*w0.y + hv.y*w1.y + hv.z*w2.y + hv.w*w3.y;
            acc[i].z += hv.x*w0.z + hv.y*w1.z + hv.z*w2.z + hv.w*w3.z;
            acc[i].w += hv.x*w0.w + hv.y*w1.w + hv.z*w2.w + hv.w*w3.w;
        }
    }

    float4 bv = {0,0,0,0};
    if (EPI) bv = ((const float4*)bias)[jq];
    float4 sv = {0,0,0,0}, qv = {0,0,0,0};
#pragma unroll
    for (int i = 0; i < NPT; ++i) {
        float4 a = acc[i];
        if (EPI) {
            a.x += bv.x; a.y += bv.y; a.z += bv.z; a.w += bv.w;
            if (RELU) {
                a.x = fmaxf(a.x, 0.f); a.y = fmaxf(a.y, 0.f);
                a.z = fmaxf(a.z, 0.f); a.w = fmaxf(a.w, 0.f);
            }
        }
        if (val[i]) {
            ((float4*)m)[(node0 + i) * TPN + jq] = a;
            if (EPI) {
                sv.x += a.x; sv.y += a.y; sv.z += a.z; sv.w += a.w;
                qv.x += a.x*a.x; qv.y += a.y*a.y; qv.z += a.z*a.z; qv.w += a.w*a.w;
            }
        }
    }
    if (EPI) {
        for (int off = TPN; off < 64; off <<= 1) {
            sv.x += __shfl_down(sv.x, off, 64); sv.y += __shfl_down(sv.y, off, 64);
            sv.z += __shfl_down(sv.z, off, 64); sv.w += __shfl_down(sv.w, off, 64);
            qv.x += __shfl_down(qv.x, off, 64); qv.y += __shfl_down(qv.y, off, 64);
            qv.z += __shfl_down(qv.z, off, 64); qv.w += __shfl_down(qv.w, off, 64);
        }
        int lane = tid & 63;
        if (lane < TPN) {
            atomicAdd(&ls[4*lane+0], sv.x); atomicAdd(&ls[4*lane+1], sv.y);
            atomicAdd(&ls[4*lane+2], sv.z); atomicAdd(&ls[4*lane+3], sv.w);
            atomicAdd(&lq[4*lane+0], qv.x); atomicAdd(&lq[4*lane+1], qv.y);
            atomicAdd(&lq[4*lane+2], qv.z); atomicAdd(&lq[4*lane+3], qv.w);
        }
        __syncthreads();
        int bkt = (blockIdx.x & (NBUCKET - 1)) * 256;
        if (tid < DOUT) {
            atomicAdd(&part[bkt + tid], ls[tid]);
            atomicAdd(&part[bkt + 128 + tid], lq[tid]);
        }
    }
}

// ---------------- BN finalize (self-zeroing buckets) ----------------
__global__ void k_finalize(float* part, const float* __restrict__ g, const float* __restrict__ bt,
                           float* scale, float* shift, int dout, int n) {
    int j = threadIdx.x;
    if (j >= dout) return;
    float s = 0.f, q = 0.f;
    for (int b = 0; b < NBUCKET; ++b) {
        s += part[b * 256 + j];       part[b * 256 + j] = 0.f;
        q += part[b * 256 + 128 + j]; part[b * 256 + 128 + j] = 0.f;
    }
    float mu = s / n;
    float var = q / n - mu * mu;
    float a = g[j] * rsqrtf(var + 1e-5f);
    scale[j] = a;
    shift[j] = bt[j] - mu * a;
}

// ---------------- fused pool (BN5 inline) + MLP head, atomic-free ----------------
__global__ void k_poolhead(const float* __restrict__ h, const int* __restrict__ batch,
                           const float* __restrict__ scale, const float* __restrict__ shift,
                           const float* __restrict__ fc1w, const float* __restrict__ fc1b,
                           const float* __restrict__ fc2w, const float* __restrict__ fc2b,
                           float* __restrict__ out, int n) {
    __shared__ float tmp[256];
    __shared__ float pl[128];
    int g = blockIdx.x;
    int tid = threadIdx.x;
    int j = tid & 127, part = tid >> 7;
    int a = 0, b = n;
    while (a < b) { int mid = (a + b) >> 1; if (batch[mid] < g) a = mid + 1; else b = mid; }
    int lo = a;
    b = n;
    while (a < b) { int mid = (a + b) >> 1; if (batch[mid] < g + 1) a = mid + 1; else b = mid; }
    int hi = a;

    float acc = 0.f;
    for (int node = lo + part; node < hi; node += 2) acc += h[(long)node * 128 + j];
    tmp[tid] = acc;
    __syncthreads();
    if (tid < 128) {
        float cnt = (float)(hi - lo);
        float p = scale[tid] * (tmp[tid] + tmp[tid + 128]) + shift[tid] * cnt;
        pl[tid] = fmaxf(p, 0.f);
    }
    __syncthreads();
    if (tid < 64) {
        float v1 = fc1b[tid];
        for (int k = 0; k < 128; ++k) v1 += pl[k] * fc1w[k * 64 + tid];
        v1 = fmaxf(v1, 0.f);
        float v = v1 * fc2w[tid];
        for (int off = 32; off > 0; off >>= 1) v += __shfl_down(v, off, 64);
        if (tid == 0) out[g] = v + fc2b[0];
    }
}

// ---------------- driver ----------------
extern "C" void kernel_launch(void* const* d_in, const int* in_sizes, int n_in,
                              void* d_out, int out_size, void* d_ws, size_t ws_size,
                              hipStream_t stream) {
    const float* x     = (const float*)d_in[0];
    const int*   ei    = (const int*)d_in[1];
    const float* ew    = (const float*)d_in[2];
    const int*   batch = (const int*)d_in[3];
    const float *W[5], *b[5], *gm[5], *bt[5];
    for (int i = 0; i < 5; ++i) {
        W[i]  = (const float*)d_in[4 + 4 * i];
        b[i]  = (const float*)d_in[5 + 4 * i];
        gm[i] = (const float*)d_in[6 + 4 * i];
        bt[i] = (const float*)d_in[7 + 4 * i];
    }
    const float* fc1w = (const float*)d_in[24];
    const float* fc1b = (const float*)d_in[25];
    const float* fc2w = (const float*)d_in[26];
    const float* fc2b = (const float*)d_in[27];
    float* out = (float*)d_out;

    // workspace layout (16B-aligned chunks)
    char* wsb = (char*)d_ws;
    float* dis    = (float*)wsb;  wsb += sizeof(float) * NN;          // 200000 (16B mult)
    int*   ptr    = (int*)wsb;    wsb += sizeof(int) * (NN + 4);      // padded
    int*   cursor = (int*)wsb;    wsb += sizeof(int) * NN;
    int*   bsum   = (int*)wsb;    wsb += sizeof(int) * 256;
    int2*  csr    = (int2*)wsb;   wsb += sizeof(int2) * NE;
    float* part   = (float*)wsb;  wsb += sizeof(float) * NBUCKET * 256;
    float* scl    = (float*)wsb;  wsb += sizeof(float) * 5 * 128;
    float* shf    = (float*)wsb;  wsb += sizeof(float) * 5 * 128;
    float* buf1   = (float*)wsb;  wsb += sizeof(float) * (long)NN * 128;
    float* buf2   = (float*)wsb;  wsb += sizeof(float) * (long)NN * 128;

    const int* row = ei;
    const int* col = ei + NE;
    const int B = 256;
    const int NB_N = (NN + B - 1) / B;   // 196
    const int NB_E = (NE + B - 1) / B;

    // prologue: CSR build, then degrees/norms from CSR (atomic-light)
    k_init<<<NB_N, B, 0, stream>>>(cursor, part, NN);
    k_hist<<<NCHUNK * HBLK, B, 0, stream>>>(col, cursor, NE);
    k_scan1<<<NB_N, B, 0, stream>>>(cursor, ptr, bsum, NN);
    k_scan2<<<1, 256, 0, stream>>>(bsum, NB_N);
    k_scan3<<<NB_N, B, 0, stream>>>(ptr, bsum, NN, NE);
    k_copy_int<<<NB_N, B, 0, stream>>>(ptr, cursor, NN);
    k_fill<<<NB_E, B, 0, stream>>>(row, col, ew, cursor, csr, NE);
    k_degdis<<<NB_N, B, 0, stream>>>(ptr, csr, dis, NN);
    k_scale<<<NB_N, B, 0, stream>>>(ptr, csr, dis, NN);

    auto grid4 = [](long threads) { return (int)((threads + 255) / 256); };
    auto ggrid = [](int npb) { return (NN + npb - 1) / npb; };

    // L1: gemm 128->16 (NPT=2), gather16 + bias+relu+stats
    k_gemm<128, 16, 0, 0, 2><<<ggrid((256/4)*2), B, 0, stream>>>(x, W[0], b[0], part, buf1, NN);
    k_gather<16, 0, 0, 1><<<grid4((long)NN * 4), B, 0, stream>>>(buf1, ptr, csr, dis,
                                                                 nullptr, nullptr, b[0], part, buf2, NN);
    k_finalize<<<1, 128, 0, stream>>>(part, gm[0], bt[0], scl + 0, shf + 0, 16, NN);

    // L2: gather16 (BN1 hoisted), gemm 16->32 + bias+relu+stats
    k_gather<16, 1, 0, 0><<<grid4((long)NN * 4), B, 0, stream>>>(buf2, ptr, csr, dis,
                                                                 scl + 0, shf + 0, nullptr, nullptr, buf1, NN);
    k_gemm<16, 32, 1, 1, 4><<<ggrid((256/8)*4), B, 0, stream>>>(buf1, W[1], b[1], part, buf2, NN);
    k_finalize<<<1, 128, 0, stream>>>(part, gm[1], bt[1], scl + 128, shf + 128, 32, NN);

    // L3: gather32 (BN2 hoisted), gemm 32->64 + bias+relu+stats
    k_gather<32, 1, 0, 0><<<grid4((long)NN * 8), B, 0, stream>>>(buf2, ptr, csr, dis,
                                                                 scl + 128, shf + 128, nullptr, nullptr, buf1, NN);
    k_gemm<32, 64, 1, 1, 4><<<ggrid((256/16)*4), B, 0, stream>>>(buf1, W[2], b[2], part, buf2, NN);
    k_finalize<<<1, 128, 0, stream>>>(part, gm[2], bt[2], scl + 256, shf + 256, 64, NN);

    // L4: gather64 (BN3 hoisted), gemm 64->64 + bias+stats (relu post-BN)
    k_gather<64, 1, 0, 0><<<grid4((long)NN * 16), B, 0, stream>>>(buf2, ptr, csr, dis,
                                                                  scl + 256, shf + 256, nullptr, nullptr, buf1, NN);
    k_gemm<64, 64, 0, 1, 4><<<ggrid((256/16)*4), B, 0, stream>>>(buf1, W[3], b[3], part, buf2, NN);
    k_finalize<<<1, 128, 0, stream>>>(part, gm[3], bt[3], scl + 384, shf + 384, 64, NN);

    // L5: gather64 (BN4 + relu per-edge), gemm 64->128 + bias+stats
    k_gather<64, 0, 1, 0><<<grid4((long)NN * 16), B, 0, stream>>>(buf2, ptr, csr, dis,
                                                                  scl + 384, shf + 384, nullptr, nullptr, buf1, NN);
    k_gemm<64, 128, 0, 1, 4><<<ggrid((256/32)*4), B, 0, stream>>>(buf1, W[4], b[4], part, buf2, NN);
    k_finalize<<<1, 128, 0, stream>>>(part, gm[4], bt[4], scl + 512, shf + 512, 128, NN);

    // fused pool (BN5) + head
    k_poolhead<<<NG, 256, 0, stream>>>(buf2, batch, scl + 512, shf + 512,
                                       fc1w, fc1b, fc2w, fc2b, out, NN);
}

// Round 6
// 515.261 us; speedup vs baseline: 1.3573x; 1.3573x over previous
//
#include <hip/hip_runtime.h>

#define NN 50000
#define NE 800000
#define NG 256
#define NBUCKET 64

// ---------------- prologue ----------------
// cnt=0, part buckets = 0
__global__ void k_init(int* cnt, float* part, int n) {
    int i = blockIdx.x * blockDim.x + threadIdx.x;
    if (i < n) cnt[i] = 0;
    if (i < NBUCKET * 256) part[i] = 0.f;
}

// flat global-atomic histogram: 800k atomics @ ~21G/s ~= 37us (measured wall, R4 k_edge)
__global__ void k_hist(const int* __restrict__ col, int* __restrict__ cnt, int e) {
    int i = blockIdx.x * blockDim.x + threadIdx.x;
    if (i < e) atomicAdd(&cnt[col[i]], 1);
}

__global__ void k_scan1(const int* __restrict__ in, int* __restrict__ out,
                        int* __restrict__ bsum, int n) {
    __shared__ int s[256];
    int i = blockIdx.x * 256 + threadIdx.x;
    int v = (i < n) ? in[i] : 0;
    s[threadIdx.x] = v;
    __syncthreads();
    for (int off = 1; off < 256; off <<= 1) {
        int t = (threadIdx.x >= off) ? s[threadIdx.x - off] : 0;
        __syncthreads();
        s[threadIdx.x] += t;
        __syncthreads();
    }
    if (i < n) out[i] = s[threadIdx.x] - v;  // exclusive
    if (threadIdx.x == 255) bsum[blockIdx.x] = s[255];
}

__global__ void k_scan2(int* bsum, int nb) {
    __shared__ int s[256];
    int v = (threadIdx.x < nb) ? bsum[threadIdx.x] : 0;
    s[threadIdx.x] = v;
    __syncthreads();
    for (int off = 1; off < 256; off <<= 1) {
        int t = (threadIdx.x >= off) ? s[threadIdx.x - off] : 0;
        __syncthreads();
        s[threadIdx.x] += t;
        __syncthreads();
    }
    if (threadIdx.x < nb) bsum[threadIdx.x] = s[threadIdx.x] - v;
}

// finalize ptr AND seed cursor in one pass (fused copy)
__global__ void k_scan3(int* __restrict__ ptr, int* __restrict__ cursor,
                        const int* __restrict__ bsum, int n, int total) {
    int i = blockIdx.x * 256 + threadIdx.x;
    if (i < n) {
        int v = ptr[i] + bsum[blockIdx.x];
        ptr[i] = v;
        cursor[i] = v;
    }
    if (i == 0) ptr[n] = total;
}

// place edges: csr[p] = {src, raw ew}; cursor pre-loaded with ptr
__global__ void k_fill(const int* __restrict__ row, const int* __restrict__ col,
                       const float* __restrict__ ew, int* cursor, int2* __restrict__ csr, int e) {
    int i = blockIdx.x * blockDim.x + threadIdx.x;
    if (i < e) {
        int c = col[i];
        int p = atomicAdd(&cursor[c], 1);
        csr[p] = make_int2(row[i], __float_as_int(ew[i]));
    }
}

// deg[c] = 1 (self loop) + sum of raw ew over segment; dis = rsqrt (atomic-free)
__global__ void k_degdis(const int* __restrict__ ptr, const int2* __restrict__ csr,
                         float* __restrict__ dis, int n) {
    int i = blockIdx.x * blockDim.x + threadIdx.x;
    if (i >= n) return;
    float s = 1.0f;
    int p1 = ptr[i + 1];
    for (int p = ptr[i]; p < p1; ++p) s += __int_as_float(csr[p].y);
    dis[i] = rsqrtf(s);   // s >= 1 > 0 always
}

// csr[p].w *= dis[src]*dis[c]  (in place)
__global__ void k_scale(const int* __restrict__ ptr, int2* __restrict__ csr,
                        const float* __restrict__ dis, int n) {
    int i = blockIdx.x * blockDim.x + threadIdx.x;
    if (i >= n) return;
    float dc = dis[i];
    int p1 = ptr[i + 1];
    for (int p = ptr[i]; p < p1; ++p) {
        int2 v = csr[p];
        csr[p].y = __float_as_int(dis[v.x] * __int_as_float(v.y) * dc);
    }
}

// ---------------- gather ----------------
// POSTAFF (L2/L3/L4): out = sc*A + sh*(dis^2 + sum w)   [BN linear, hoisted]
// PREAFF  (L5): per-edge relu(sc*u+sh)
// EPI     (L1): out = relu(A + bias), channel stats into buckets
template <int D, int POSTAFF, int PREAFF, int EPI>
__global__ void k_gather(const float* __restrict__ src, const int* __restrict__ ptr,
                         const int2* __restrict__ csr,
                         const float* __restrict__ dis,
                         const float* __restrict__ scale, const float* __restrict__ shift,
                         const float* __restrict__ bias, float* __restrict__ part,
                         float* __restrict__ out, int n) {
    const int TPN = D / 4;
    __shared__ float ls[EPI ? D : 1], lq[EPI ? D : 1];
    int tid = threadIdx.x;
    if (EPI) {
        if (tid < D) { ls[tid] = 0.f; lq[tid] = 0.f; }
        __syncthreads();
    }
    int t = blockIdx.x * blockDim.x + tid;
    int node = t / TPN;
    int l4 = t - node * TPN;
    bool valid = node < n;
    int nc = valid ? node : n - 1;

    float4 sc = {0,0,0,0}, sh = {0,0,0,0};
    if (POSTAFF || PREAFF) {
        sc = ((const float4*)scale)[l4];
        sh = ((const float4*)shift)[l4];
    }
    const float4* s4 = (const float4*)src;
    float d = dis[nc];
    float w0 = d * d;
    float4 v = s4[nc * TPN + l4];
    if (PREAFF) {
        v.x = fmaxf(sc.x * v.x + sh.x, 0.f); v.y = fmaxf(sc.y * v.y + sh.y, 0.f);
        v.z = fmaxf(sc.z * v.z + sh.z, 0.f); v.w = fmaxf(sc.w * v.w + sh.w, 0.f);
    }
    float4 acc = { w0 * v.x, w0 * v.y, w0 * v.z, w0 * v.w };
    float sumw = w0;
    int p0 = ptr[nc], p1 = ptr[nc + 1];
    int p = p0;
    for (; p + 4 <= p1; p += 4) {
        int2 c0 = csr[p], c1 = csr[p+1], c2 = csr[p+2], c3 = csr[p+3];
        float e0 = __int_as_float(c0.y), e1 = __int_as_float(c1.y);
        float e2 = __int_as_float(c2.y), e3 = __int_as_float(c3.y);
        float4 u0 = s4[c0.x * TPN + l4];
        float4 u1 = s4[c1.x * TPN + l4];
        float4 u2 = s4[c2.x * TPN + l4];
        float4 u3 = s4[c3.x * TPN + l4];
        if (PREAFF) {
            u0.x = fmaxf(sc.x*u0.x+sh.x,0.f); u0.y = fmaxf(sc.y*u0.y+sh.y,0.f);
            u0.z = fmaxf(sc.z*u0.z+sh.z,0.f); u0.w = fmaxf(sc.w*u0.w+sh.w,0.f);
            u1.x = fmaxf(sc.x*u1.x+sh.x,0.f); u1.y = fmaxf(sc.y*u1.y+sh.y,0.f);
            u1.z = fmaxf(sc.z*u1.z+sh.z,0.f); u1.w = fmaxf(sc.w*u1.w+sh.w,0.f);
            u2.x = fmaxf(sc.x*u2.x+sh.x,0.f); u2.y = fmaxf(sc.y*u2.y+sh.y,0.f);
            u2.z = fmaxf(sc.z*u2.z+sh.z,0.f); u2.w = fmaxf(sc.w*u2.w+sh.w,0.f);
            u3.x = fmaxf(sc.x*u3.x+sh.x,0.f); u3.y = fmaxf(sc.y*u3.y+sh.y,0.f);
            u3.z = fmaxf(sc.z*u3.z+sh.z,0.f); u3.w = fmaxf(sc.w*u3.w+sh.w,0.f);
        }
        acc.x += e0*u0.x + e1*u1.x + e2*u2.x + e3*u3.x;
        acc.y += e0*u0.y + e1*u1.y + e2*u2.y + e3*u3.y;
        acc.z += e0*u0.z + e1*u1.z + e2*u2.z + e3*u3.z;
        acc.w += e0*u0.w + e1*u1.w + e2*u2.w + e3*u3.w;
        if (POSTAFF) sumw += e0 + e1 + e2 + e3;
    }
    for (; p < p1; ++p) {
        int2 ce = csr[p];
        float w = __int_as_float(ce.y);
        float4 u = s4[ce.x * TPN + l4];
        if (PREAFF) {
            u.x = fmaxf(sc.x*u.x+sh.x,0.f); u.y = fmaxf(sc.y*u.y+sh.y,0.f);
            u.z = fmaxf(sc.z*u.z+sh.z,0.f); u.w = fmaxf(sc.w*u.w+sh.w,0.f);
        }
        acc.x += w*u.x; acc.y += w*u.y; acc.z += w*u.z; acc.w += w*u.w;
        if (POSTAFF) sumw += w;
    }
    if (POSTAFF) {
        acc.x = sc.x * acc.x + sh.x * sumw;
        acc.y = sc.y * acc.y + sh.y * sumw;
        acc.z = sc.z * acc.z + sh.z * sumw;
        acc.w = sc.w * acc.w + sh.w * sumw;
    }
    if (EPI) {
        float4 b = ((const float4*)bias)[l4];
        acc.x = fmaxf(acc.x + b.x, 0.f);
        acc.y = fmaxf(acc.y + b.y, 0.f);
        acc.z = fmaxf(acc.z + b.z, 0.f);
        acc.w = fmaxf(acc.w + b.w, 0.f);
        if (valid) ((float4*)out)[nc * TPN + l4] = acc;
        float s0 = valid ? acc.x : 0.f, s1 = valid ? acc.y : 0.f;
        float s2 = valid ? acc.z : 0.f, s3 = valid ? acc.w : 0.f;
        float q0 = s0*s0, q1 = s1*s1, q2 = s2*s2, q3 = s3*s3;
        for (int off = TPN; off < 64; off <<= 1) {
            s0 += __shfl_down(s0, off, 64); s1 += __shfl_down(s1, off, 64);
            s2 += __shfl_down(s2, off, 64); s3 += __shfl_down(s3, off, 64);
            q0 += __shfl_down(q0, off, 64); q1 += __shfl_down(q1, off, 64);
            q2 += __shfl_down(q2, off, 64); q3 += __shfl_down(q3, off, 64);
        }
        int lane = tid & 63;
        if (lane < TPN) {
            atomicAdd(&ls[4*lane+0], s0); atomicAdd(&ls[4*lane+1], s1);
            atomicAdd(&ls[4*lane+2], s2); atomicAdd(&ls[4*lane+3], s3);
            atomicAdd(&lq[4*lane+0], q0); atomicAdd(&lq[4*lane+1], q1);
            atomicAdd(&lq[4*lane+2], q2); atomicAdd(&lq[4*lane+3], q3);
        }
        __syncthreads();
        int bkt = (blockIdx.x & (NBUCKET - 1)) * 256;
        if (tid < D) {
            atomicAdd(&part[bkt + tid], ls[tid]);
            atomicAdd(&part[bkt + 128 + tid], lq[tid]);
        }
    } else {
        if (valid) ((float4*)out)[nc * TPN + l4] = acc;
    }
}

// ---------------- node-blocked GEMM: NPT nodes x 4 outputs per thread ----------------
template <int DIN, int DOUT, int RELU, int EPI, int NPT>
__global__ void k_gemm(const float* __restrict__ h, const float* __restrict__ W,
                       const float* __restrict__ bias, float* __restrict__ part,
                       float* __restrict__ m, int n) {
    const int TPN = DOUT / 4;
    const int GPB = 256 / TPN;
    __shared__ float Wl[DIN * DOUT];
    __shared__ float ls[EPI ? DOUT : 1], lq[EPI ? DOUT : 1];
    int tid = threadIdx.x;
    for (int i = tid; i < DIN * DOUT / 4; i += 256)
        ((float4*)Wl)[i] = ((const float4*)W)[i];
    if (EPI && tid < DOUT) { ls[tid] = 0.f; lq[tid] = 0.f; }
    __syncthreads();

    int jq = tid % TPN;
    int group = tid / TPN;
    int node0 = (blockIdx.x * GPB + group) * NPT;
    const float4* h4 = (const float4*)h;
    int hb[NPT];
    bool val[NPT];
#pragma unroll
    for (int i = 0; i < NPT; ++i) {
        int nd = node0 + i;
        val[i] = nd < n;
        hb[i] = (val[i] ? nd : n - 1) * (DIN / 4);
    }
    float4 acc[NPT];
#pragma unroll
    for (int i = 0; i < NPT; ++i) acc[i] = {0.f, 0.f, 0.f, 0.f};

#pragma unroll 4
    for (int k4 = 0; k4 < DIN / 4; ++k4) {
        const float* wb = &Wl[(k4 * 4) * DOUT + jq * 4];
        float4 w0 = *(const float4*)(wb);
        float4 w1 = *(const float4*)(wb + DOUT);
        float4 w2 = *(const float4*)(wb + 2 * DOUT);
        float4 w3 = *(const float4*)(wb + 3 * DOUT);
#pragma unroll
        for (int i = 0; i < NPT; ++i) {
            float4 hv = h4[hb[i] + k4];
            acc[i].x += hv.x*w0.x + hv.y*w1.x + hv.z*w2.x + hv.w*w3.x;
            acc[i].y += hv.x*w0.y + hv.y*w1.y + hv.z*w2.y + hv.w*w3.y;
            acc[i].z += hv.x*w0.z + hv.y*w1.z + hv.z*w2.z + hv.w*w3.z;
            acc[i].w += hv.x*w0.w + hv.y*w1.w + hv.z*w2.w + hv.w*w3.w;
        }
    }

    float4 bv = {0,0,0,0};
    if (EPI) bv = ((const float4*)bias)[jq];
    float4 sv = {0,0,0,0}, qv = {0,0,0,0};
#pragma unroll
    for (int i = 0; i < NPT; ++i) {
        float4 a = acc[i];
        if (EPI) {
            a.x += bv.x; a.y += bv.y; a.z += bv.z; a.w += bv.w;
            if (RELU) {
                a.x = fmaxf(a.x, 0.f); a.y = fmaxf(a.y, 0.f);
                a.z = fmaxf(a.z, 0.f); a.w = fmaxf(a.w, 0.f);
            }
        }
        if (val[i]) {
            ((float4*)m)[(node0 + i) * TPN + jq] = a;
            if (EPI) {
                sv.x += a.x; sv.y += a.y; sv.z += a.z; sv.w += a.w;
                qv.x += a.x*a.x; qv.y += a.y*a.y; qv.z += a.z*a.z; qv.w += a.w*a.w;
            }
        }
    }
    if (EPI) {
        for (int off = TPN; off < 64; off <<= 1) {
            sv.x += __shfl_down(sv.x, off, 64); sv.y += __shfl_down(sv.y, off, 64);
            sv.z += __shfl_down(sv.z, off, 64); sv.w += __shfl_down(sv.w, off, 64);
            qv.x += __shfl_down(qv.x, off, 64); qv.y += __shfl_down(qv.y, off, 64);
            qv.z += __shfl_down(qv.z, off, 64); qv.w += __shfl_down(qv.w, off, 64);
        }
        int lane = tid & 63;
        if (lane < TPN) {
            atomicAdd(&ls[4*lane+0], sv.x); atomicAdd(&ls[4*lane+1], sv.y);
            atomicAdd(&ls[4*lane+2], sv.z); atomicAdd(&ls[4*lane+3], sv.w);
            atomicAdd(&lq[4*lane+0], qv.x); atomicAdd(&lq[4*lane+1], qv.y);
            atomicAdd(&lq[4*lane+2], qv.z); atomicAdd(&lq[4*lane+3], qv.w);
        }
        __syncthreads();
        int bkt = (blockIdx.x & (NBUCKET - 1)) * 256;
        if (tid < DOUT) {
            atomicAdd(&part[bkt + tid], ls[tid]);
            atomicAdd(&part[bkt + 128 + tid], lq[tid]);
        }
    }
}

// ---------------- BN finalize (self-zeroing buckets) ----------------
__global__ void k_finalize(float* part, const float* __restrict__ g, const float* __restrict__ bt,
                           float* scale, float* shift, int dout, int n) {
    int j = threadIdx.x;
    if (j >= dout) return;
    float s = 0.f, q = 0.f;
    for (int b = 0; b < NBUCKET; ++b) {
        s += part[b * 256 + j];       part[b * 256 + j] = 0.f;
        q += part[b * 256 + 128 + j]; part[b * 256 + 128 + j] = 0.f;
    }
    float mu = s / n;
    float var = q / n - mu * mu;
    float a = g[j] * rsqrtf(var + 1e-5f);
    scale[j] = a;
    shift[j] = bt[j] - mu * a;
}

// ---------------- fused pool (BN5 inline) + MLP head, atomic-free ----------------
__global__ void k_poolhead(const float* __restrict__ h, const int* __restrict__ batch,
                           const float* __restrict__ scale, const float* __restrict__ shift,
                           const float* __restrict__ fc1w, const float* __restrict__ fc1b,
                           const float* __restrict__ fc2w, const float* __restrict__ fc2b,
                           float* __restrict__ out, int n) {
    __shared__ float tmp[256];
    __shared__ float pl[128];
    int g = blockIdx.x;
    int tid = threadIdx.x;
    int j = tid & 127, part = tid >> 7;
    int a = 0, b = n;
    while (a < b) { int mid = (a + b) >> 1; if (batch[mid] < g) a = mid + 1; else b = mid; }
    int lo = a;
    b = n;
    while (a < b) { int mid = (a + b) >> 1; if (batch[mid] < g + 1) a = mid + 1; else b = mid; }
    int hi = a;

    float acc = 0.f;
    for (int node = lo + part; node < hi; node += 2) acc += h[(long)node * 128 + j];
    tmp[tid] = acc;
    __syncthreads();
    if (tid < 128) {
        float cnt = (float)(hi - lo);
        float p = scale[tid] * (tmp[tid] + tmp[tid + 128]) + shift[tid] * cnt;
        pl[tid] = fmaxf(p, 0.f);
    }
    __syncthreads();
    if (tid < 64) {
        float v1 = fc1b[tid];
        for (int k = 0; k < 128; ++k) v1 += pl[k] * fc1w[k * 64 + tid];
        v1 = fmaxf(v1, 0.f);
        float v = v1 * fc2w[tid];
        for (int off = 32; off > 0; off >>= 1) v += __shfl_down(v, off, 64);
        if (tid == 0) out[g] = v + fc2b[0];
    }
}

// ---------------- driver ----------------
extern "C" void kernel_launch(void* const* d_in, const int* in_sizes, int n_in,
                              void* d_out, int out_size, void* d_ws, size_t ws_size,
                              hipStream_t stream) {
    const float* x     = (const float*)d_in[0];
    const int*   ei    = (const int*)d_in[1];
    const float* ew    = (const float*)d_in[2];
    const int*   batch = (const int*)d_in[3];
    const float *W[5], *b[5], *gm[5], *bt[5];
    for (int i = 0; i < 5; ++i) {
        W[i]  = (const float*)d_in[4 + 4 * i];
        b[i]  = (const float*)d_in[5 + 4 * i];
        gm[i] = (const float*)d_in[6 + 4 * i];
        bt[i] = (const float*)d_in[7 + 4 * i];
    }
    const float* fc1w = (const float*)d_in[24];
    const float* fc1b = (const float*)d_in[25];
    const float* fc2w = (const float*)d_in[26];
    const float* fc2b = (const float*)d_in[27];
    float* out = (float*)d_out;

    // workspace layout (16B-aligned chunks)
    char* wsb = (char*)d_ws;
    float* dis    = (float*)wsb;  wsb += sizeof(float) * NN;
    int*   ptr    = (int*)wsb;    wsb += sizeof(int) * (NN + 4);
    int*   cursor = (int*)wsb;    wsb += sizeof(int) * NN;
    int*   bsum   = (int*)wsb;    wsb += sizeof(int) * 256;
    int2*  csr    = (int2*)wsb;   wsb += sizeof(int2) * NE;
    float* part   = (float*)wsb;  wsb += sizeof(float) * NBUCKET * 256;
    float* scl    = (float*)wsb;  wsb += sizeof(float) * 5 * 128;
    float* shf    = (float*)wsb;  wsb += sizeof(float) * 5 * 128;
    float* buf1   = (float*)wsb;  wsb += sizeof(float) * (long)NN * 128;
    float* buf2   = (float*)wsb;  wsb += sizeof(float) * (long)NN * 128;

    const int* row = ei;
    const int* col = ei + NE;
    const int B = 256;
    const int NB_N = (NN + B - 1) / B;   // 196
    const int NB_E = (NE + B - 1) / B;

    // prologue: CSR build, then degrees/norms from CSR
    k_init<<<NB_N, B, 0, stream>>>(cursor, part, NN);
    k_hist<<<NB_E, B, 0, stream>>>(col, cursor, NE);
    k_scan1<<<NB_N, B, 0, stream>>>(cursor, ptr, bsum, NN);
    k_scan2<<<1, 256, 0, stream>>>(bsum, NB_N);
    k_scan3<<<NB_N, B, 0, stream>>>(ptr, cursor, bsum, NN, NE);
    k_fill<<<NB_E, B, 0, stream>>>(row, col, ew, cursor, csr, NE);
    k_degdis<<<NB_N, B, 0, stream>>>(ptr, csr, dis, NN);
    k_scale<<<NB_N, B, 0, stream>>>(ptr, csr, dis, NN);

    auto grid4 = [](long threads) { return (int)((threads + 255) / 256); };
    auto ggrid = [](int npb) { return (NN + npb - 1) / npb; };

    // L1: gemm 128->16 (NPT=2), gather16 + bias+relu+stats
    k_gemm<128, 16, 0, 0, 2><<<ggrid((256/4)*2), B, 0, stream>>>(x, W[0], b[0], part, buf1, NN);
    k_gather<16, 0, 0, 1><<<grid4((long)NN * 4), B, 0, stream>>>(buf1, ptr, csr, dis,
                                                                 nullptr, nullptr, b[0], part, buf2, NN);
    k_finalize<<<1, 128, 0, stream>>>(part, gm[0], bt[0], scl + 0, shf + 0, 16, NN);

    // L2: gather16 (BN1 hoisted), gemm 16->32 + bias+relu+stats
    k_gather<16, 1, 0, 0><<<grid4((long)NN * 4), B, 0, stream>>>(buf2, ptr, csr, dis,
                                                                 scl + 0, shf + 0, nullptr, nullptr, buf1, NN);
    k_gemm<16, 32, 1, 1, 4><<<ggrid((256/8)*4), B, 0, stream>>>(buf1, W[1], b[1], part, buf2, NN);
    k_finalize<<<1, 128, 0, stream>>>(part, gm[1], bt[1], scl + 128, shf + 128, 32, NN);

    // L3: gather32 (BN2 hoisted), gemm 32->64 + bias+relu+stats
    k_gather<32, 1, 0, 0><<<grid4((long)NN * 8), B, 0, stream>>>(buf2, ptr, csr, dis,
                                                                 scl + 128, shf + 128, nullptr, nullptr, buf1, NN);
    k_gemm<32, 64, 1, 1, 4><<<ggrid((256/16)*4), B, 0, stream>>>(buf1, W[2], b[2], part, buf2, NN);
    k_finalize<<<1, 128, 0, stream>>>(part, gm[2], bt[2], scl + 256, shf + 256, 64, NN);

    // L4: gather64 (BN3 hoisted), gemm 64->64 + bias+stats (relu post-BN)
    k_gather<64, 1, 0, 0><<<grid4((long)NN * 16), B, 0, stream>>>(buf2, ptr, csr, dis,
                                                                  scl + 256, shf + 256, nullptr, nullptr, buf1, NN);
    k_gemm<64, 64, 0, 1, 4><<<ggrid((256/16)*4), B, 0, stream>>>(buf1, W[3], b[3], part, buf2, NN);
    k_finalize<<<1, 128, 0, stream>>>(part, gm[3], bt[3], scl + 384, shf + 384, 64, NN);

    // L5: gather64 (BN4 + relu per-edge), gemm 64->128 + bias+stats
    k_gather<64, 0, 1, 0><<<grid4((long)NN * 16), B, 0, stream>>>(buf2, ptr, csr, dis,
                                                                  scl + 384, shf + 384, nullptr, nullptr, buf1, NN);
    k_gemm<64, 128, 0, 1, 4><<<ggrid((256/32)*4), B, 0, stream>>>(buf1, W[4], b[4], part, buf2, NN);
    k_finalize<<<1, 128, 0, stream>>>(part, gm[4], bt[4], scl + 512, shf + 512, 128, NN);

    // fused pool (BN5) + head
    k_poolhead<<<NG, 256, 0, stream>>>(buf2, batch, scl + 512, shf + 512,
                                       fc1w, fc1b, fc2w, fc2b, out, NN);
}